// Round 3
// baseline (844.242 us; speedup 1.0000x reference)
//
#include <hip/hip_runtime.h>
#include <math.h>

#define H 8
#define KK 2048
#define DD 64
#define HIDN 1024
#define BB 8192
#define TWO_D 128
#define OO 128

// ws float-element offsets
// [0, 524288)      : cb_hi  (bf16, [h][k][64], 1048576 shorts)
// [524288, 1048576): cb_lo  (bf16, [h][k][64])
#define WS_CSQ   1048576      // H*KK f32
#define WS_ZSQ   1064960      // BB*H f32
#define WS_IDX   1130496      // BB*H (int)
#define WS_AVGP  1196032      // H*KK f32
#define WS_HIST  1212416      // H*KK (uint)
#define WS_ACC   1228800      // 2 doubles: commit_acc, ortho_acc
#define WS_ZERO_BYTES ((16384 + 16384 + 4) * 4)

// out float-element offsets
#define OUT_ZQ 0
#define OUT_IDX 8388608
#define OUT_COMMIT 8454144
#define OUT_CBL 8454145
#define OUT_ENT 8454146
#define OUT_ORTHO 8454147
#define OUT_ZH 8454148

typedef __attribute__((ext_vector_type(8))) short bf16x8;
typedef __attribute__((ext_vector_type(4))) float f32x4;

__device__ inline unsigned short bf16_rne(float x) {
    union { float f; unsigned u; } c; c.f = x;
    unsigned r = c.u + 0x7FFFu + ((c.u >> 16) & 1u);
    return (unsigned short)(r >> 16);
}
__device__ inline float bf16_f32(unsigned short h) {
    union { unsigned u; float f; } c; c.u = ((unsigned)h) << 16;
    return c.f;
}

// ---------------- k_pre: c_sq + bf16 hi/lo split of codebooks [h][k][d] ----------------
__global__ __launch_bounds__(256) void k_pre(const float* __restrict__ cb, float* __restrict__ ws) {
    int h = blockIdx.x >> 3, kb = blockIdx.x & 7;
    int k = (kb << 8) + threadIdx.x;
    const float4* row = (const float4*)(cb + (size_t)(h * KK + k) * DD);
    short* hi = (short*)ws + (size_t)(h * KK + k) * DD;
    short* lo = (short*)ws + 1048576 + (size_t)(h * KK + k) * DD;
    float s = 0.f;
#pragma unroll
    for (int p = 0; p < 8; ++p) {
        float4 v0 = row[p * 2], v1 = row[p * 2 + 1];
        float vv[8] = {v0.x, v0.y, v0.z, v0.w, v1.x, v1.y, v1.z, v1.w};
        union { short e[8]; bf16x8 v; } uh, ul;
#pragma unroll
        for (int j = 0; j < 8; ++j) {
            float x = vv[j];
            s = fmaf(x, x, s);
            unsigned short hb = bf16_rne(x);
            uh.e[j] = (short)hb;
            ul.e[j] = (short)bf16_rne(x - bf16_f32(hb));
        }
        *(bf16x8*)(hi + p * 8) = uh.v;
        *(bf16x8*)(lo + p * 8) = ul.v;
    }
    ws[WS_CSQ + h * KK + k] = s;
}

// ---------------- k1: h1=gelu(z@w1+b1); zh=h1@w2+b2; LayerNorm -> z_heads, zsq ----------------
__global__ __launch_bounds__(256, 2) void k1(const float* __restrict__ z, const float* __restrict__ w1,
                                             const float* __restrict__ b1, const float* __restrict__ w2,
                                             const float* __restrict__ b2, const float* __restrict__ lng,
                                             const float* __restrict__ lnb, float* __restrict__ out,
                                             float* __restrict__ ws) {
    __shared__ float smem[16384];
    float* ztT = smem;
    float* w1t = smem + 4352;
    int t = threadIdx.x;
    int h = blockIdx.y;
    int b0 = blockIdx.x * 64;
    int cg = t & 15, rg = t >> 4;

    float acc[4][8];
#pragma unroll
    for (int i = 0; i < 4; ++i)
#pragma unroll
        for (int j = 0; j < 8; ++j) acc[i][j] = 0.f;

    for (int kc = 0; kc < HIDN; kc += 64) {
        __syncthreads();
#pragma unroll
        for (int p = 0; p < 4; ++p) {
            int q = t + 256 * p;
            int r = q >> 4, c4 = q & 15;
            float4 v = *(const float4*)(z + (size_t)(b0 + r) * HIDN + kc + c4 * 4);
            ztT[(c4 * 4 + 0) * 68 + r] = v.x;
            ztT[(c4 * 4 + 1) * 68 + r] = v.y;
            ztT[(c4 * 4 + 2) * 68 + r] = v.z;
            ztT[(c4 * 4 + 3) * 68 + r] = v.w;
        }
#pragma unroll
        for (int p = 0; p < 8; ++p) {
            int q = t + 256 * p;
            int r = q >> 5, c4 = q & 31;
            *(float4*)(w1t + r * 128 + c4 * 4) =
                *(const float4*)(w1 + (size_t)(h * HIDN + kc + r) * TWO_D + c4 * 4);
        }
        __syncthreads();
#pragma unroll 8
        for (int k = 0; k < 64; ++k) {
            float4 zv = *(const float4*)(ztT + k * 68 + rg * 4);
            float4 wa = *(const float4*)(w1t + k * 128 + cg * 8);
            float4 wb = *(const float4*)(w1t + k * 128 + cg * 8 + 4);
            float zz[4] = {zv.x, zv.y, zv.z, zv.w};
            float ww[8] = {wa.x, wa.y, wa.z, wa.w, wb.x, wb.y, wb.z, wb.w};
#pragma unroll
            for (int i = 0; i < 4; ++i)
#pragma unroll
                for (int j = 0; j < 8; ++j) acc[i][j] = fmaf(zz[i], ww[j], acc[i][j]);
        }
    }
    __syncthreads();
    float* h1t = smem;
    float* w2t = smem + 8192;
    int wswz = (rg & 7) << 2;
#pragma unroll
    for (int i = 0; i < 4; ++i)
#pragma unroll
        for (int j = 0; j < 8; ++j) {
            int c = cg * 8 + j;
            float x = acc[i][j] + b1[h * TWO_D + c];
            float gl = 0.5f * x * (1.0f + erff(x * 0.70710678118654752f));
            h1t[(rg * 4 + i) * 128 + (c ^ wswz)] = gl;
        }
#pragma unroll
    for (int p = 0; p < 8; ++p) {
        int q = t + 256 * p;
        int r = q >> 4, c4 = q & 15;
        *(float4*)(w2t + r * 64 + c4 * 4) =
            *(const float4*)(w2 + (size_t)(h * TWO_D + r) * DD + c4 * 4);
    }
    __syncthreads();

    int rg2 = t >> 4, cg2 = t & 15;
    int myswz = (rg2 & 7) << 2;
    float a2[4][4];
#pragma unroll
    for (int i = 0; i < 4; ++i)
#pragma unroll
        for (int j = 0; j < 4; ++j) a2[i][j] = 0.f;
#pragma unroll 4
    for (int i = 0; i < 128; ++i) {
        int ic = i ^ myswz;
        float hv[4];
#pragma unroll
        for (int rr = 0; rr < 4; ++rr) hv[rr] = h1t[(rg2 * 4 + rr) * 128 + ic];
        float4 wv = *(const float4*)(w2t + i * 64 + cg2 * 4);
        float ww[4] = {wv.x, wv.y, wv.z, wv.w};
#pragma unroll
        for (int rr = 0; rr < 4; ++rr)
#pragma unroll
            for (int jj = 0; jj < 4; ++jj) a2[rr][jj] = fmaf(hv[rr], ww[jj], a2[rr][jj]);
    }

#pragma unroll
    for (int rr = 0; rr < 4; ++rr)
#pragma unroll
        for (int jj = 0; jj < 4; ++jj) a2[rr][jj] += b2[h * DD + cg2 * 4 + jj];

#pragma unroll
    for (int rr = 0; rr < 4; ++rr) {
        float sloc = a2[rr][0] + a2[rr][1] + a2[rr][2] + a2[rr][3];
#pragma unroll
        for (int m = 1; m < 16; m <<= 1) sloc += __shfl_xor(sloc, m, 64);
        float muv = sloc * (1.0f / 64.0f);
        float v0 = 0.f;
#pragma unroll
        for (int jj = 0; jj < 4; ++jj) { float dv = a2[rr][jj] - muv; v0 = fmaf(dv, dv, v0); }
#pragma unroll
        for (int m = 1; m < 16; m <<= 1) v0 += __shfl_xor(v0, m, 64);
        float var = v0 * (1.0f / 64.0f);
        float rstd = 1.0f / sqrtf(var + 1e-5f);
        int row = b0 + rg2 * 4 + rr;
        float zn[4]; float ss = 0.f;
#pragma unroll
        for (int jj = 0; jj < 4; ++jj) {
            int c = cg2 * 4 + jj;
            float v = (a2[rr][jj] - muv) * rstd * lng[h * DD + c] + lnb[h * DD + c];
            zn[jj] = v; ss = fmaf(v, v, ss);
        }
#pragma unroll
        for (int m = 1; m < 16; m <<= 1) ss += __shfl_xor(ss, m, 64);
        if (cg2 == 0) ws[WS_ZSQ + row * H + h] = ss;
        float4 sv = {zn[0], zn[1], zn[2], zn[3]};
        *(float4*)(out + OUT_ZH + (size_t)(row * H + h) * DD + cg2 * 4) = sv;
    }
}

// ---------------- k2: MFMA bf16x3 distances + exact-f32 argmin refine + softmax stats ----------------
#define MARGIN 0.05f
__global__ __launch_bounds__(512, 2) void k2(const float* __restrict__ cb,
                                             float* __restrict__ out, float* __restrict__ ws) {
    __shared__ float zt[32][68];
    __shared__ float paccL[2048];
    __shared__ float redM[128];   // [bg][kg][16]
    __shared__ float redS[128];
    __shared__ float redE[128];
    __shared__ int   redK[128];

    int t = threadIdx.x;
    int h = blockIdx.y;
    int b0 = blockIdx.x * 32;
    int w = t >> 6, l = t & 63;
    int bg = w >> 2, kg = w & 3;
    int lb = l & 15, lg = l >> 4;
    int myb = b0 + bg * 16 + lb;

    for (int i = t; i < 2048; i += 512) paccL[i] = 0.f;
    {
        int r = t >> 4, c4 = t & 15;
        *(float4*)&zt[r][c4 * 4] =
            *(const float4*)(out + OUT_ZH + (size_t)((b0 + r) * H + h) * DD + c4 * 4);
    }
    __syncthreads();

    float zsq = ws[WS_ZSQ + myb * H + h];

    // B fragments (zh hi/lo) — built once, reused for all 32 k-tiles
    bf16x8 bh[2], bl[2];
#pragma unroll
    for (int s = 0; s < 2; ++s) {
        const float* zr = &zt[bg * 16 + lb][s * 32 + lg * 8];
        union { short e[8]; bf16x8 v; } uh, ul;
#pragma unroll
        for (int j = 0; j < 8; ++j) {
            float x = zr[j];
            unsigned short hb = bf16_rne(x);
            uh.e[j] = (short)hb;
            ul.e[j] = (short)bf16_rne(x - bf16_f32(hb));
        }
        bh[s] = uh.v; bl[s] = ul.v;
    }

    const short* cbhi = (const short*)ws;
    const short* cblo = (const short*)ws + 1048576;
    int kbase = kg * 512;

    f32x4 acc[32];
#pragma unroll
    for (int tt = 0; tt < 32; ++tt) acc[tt] = (f32x4){0.f, 0.f, 0.f, 0.f};

#pragma unroll
    for (int tt = 0; tt < 32; ++tt) {
        int k0 = kbase + tt * 16;
        int ofs = (h * KK + k0 + lb) * DD + lg * 8;
        bf16x8 a0s0 = *(const bf16x8*)(cbhi + ofs);
        bf16x8 a0s1 = *(const bf16x8*)(cbhi + ofs + 32);
        bf16x8 a1s0 = *(const bf16x8*)(cblo + ofs);
        bf16x8 a1s1 = *(const bf16x8*)(cblo + ofs + 32);
        f32x4 c = acc[tt];
        c = __builtin_amdgcn_mfma_f32_16x16x32_bf16(a0s0, bh[0], c, 0, 0, 0);
        c = __builtin_amdgcn_mfma_f32_16x16x32_bf16(a0s0, bl[0], c, 0, 0, 0);
        c = __builtin_amdgcn_mfma_f32_16x16x32_bf16(a1s0, bh[0], c, 0, 0, 0);
        c = __builtin_amdgcn_mfma_f32_16x16x32_bf16(a0s1, bh[1], c, 0, 0, 0);
        c = __builtin_amdgcn_mfma_f32_16x16x32_bf16(a0s1, bl[1], c, 0, 0, 0);
        c = __builtin_amdgcn_mfma_f32_16x16x32_bf16(a1s1, bh[1], c, 0, 0, 0);
        acc[tt] = c;
    }

    // pass A: dists (approx) + local min
    float Mloc = 3.4e38f;
#pragma unroll
    for (int tt = 0; tt < 32; ++tt) {
        int k0 = kbase + tt * 16;
        float4 cs = *(const float4*)(ws + WS_CSQ + h * KK + k0 + lg * 4);
        f32x4 a = acc[tt];
        float d0 = (zsq + cs.x) - 2.f * a[0];
        float d1 = (zsq + cs.y) - 2.f * a[1];
        float d2 = (zsq + cs.z) - 2.f * a[2];
        float d3 = (zsq + cs.w) - 2.f * a[3];
        acc[tt] = (f32x4){d0, d1, d2, d3};
        Mloc = fminf(Mloc, fminf(fminf(d0, d1), fminf(d2, d3)));
    }
    Mloc = fminf(Mloc, __shfl_xor(Mloc, 16));
    Mloc = fminf(Mloc, __shfl_xor(Mloc, 32));
    if (l < 16) redM[bg * 64 + kg * 16 + lb] = Mloc;
    __syncthreads();
    float Mb = fminf(fminf(redM[bg * 64 + lb], redM[bg * 64 + 16 + lb]),
                     fminf(redM[bg * 64 + 32 + lb], redM[bg * 64 + 48 + lb]));

    // pass B: exp-sum + candidate mask
    float T = Mb + MARGIN;
    float Sloc = 0.f;
    unsigned long long m0 = 0ull, m1 = 0ull;
#pragma unroll
    for (int tt = 0; tt < 32; ++tt) {
        f32x4 d = acc[tt];
#pragma unroll
        for (int r = 0; r < 4; ++r) {
            float dv = d[r];
            Sloc += __expf(Mb - dv);
            if (dv <= T) {
                if (tt < 16) m0 |= 1ull << ((tt & 15) * 4 + r);
                else         m1 |= 1ull << ((tt & 15) * 4 + r);
            }
        }
    }
    // exact f32 refinement of candidates (bitwise same fmaf order as round-1 kernel)
    float eBest = 3.4e38f; int kBest = 0x7FFFFFFF;
    {
        const float* zr0 = &zt[bg * 16 + lb][0];
#pragma unroll
        for (int half = 0; half < 2; ++half) {
            unsigned long long m = half ? m1 : m0;
            while (m) {
                int i = (int)__ffsll(m) - 1;
                m &= m - 1;
                int k = kbase + (half * 16 + (i >> 2)) * 16 + lg * 4 + (i & 3);
                const float4* crow = (const float4*)(cb + (size_t)(h * KK + k) * DD);
                float s = 0.f;
#pragma unroll 1
                for (int q = 0; q < 16; ++q) {
                    float4 cv = crow[q];
                    s = fmaf(zr0[q * 4 + 0], cv.x, s);
                    s = fmaf(zr0[q * 4 + 1], cv.y, s);
                    s = fmaf(zr0[q * 4 + 2], cv.z, s);
                    s = fmaf(zr0[q * 4 + 3], cv.w, s);
                }
                float ex = (zsq + ws[WS_CSQ + h * KK + k]) - 2.f * s;
                if (ex < eBest || (ex == eBest && k < kBest)) { eBest = ex; kBest = k; }
            }
        }
    }
#pragma unroll
    for (int off = 16; off <= 32; off <<= 1) {
        Sloc += __shfl_xor(Sloc, off);
        float oe = __shfl_xor(eBest, off);
        int ok = __shfl_xor(kBest, off);
        if (oe < eBest || (oe == eBest && ok < kBest)) { eBest = oe; kBest = ok; }
    }
    if (l < 16) {
        redS[bg * 64 + kg * 16 + lb] = Sloc;
        redE[bg * 64 + kg * 16 + lb] = eBest;
        redK[bg * 64 + kg * 16 + lb] = kBest;
    }
    __syncthreads();
    float Sb = redS[bg * 64 + lb] + redS[bg * 64 + 16 + lb] +
               redS[bg * 64 + 32 + lb] + redS[bg * 64 + 48 + lb];
    {
        eBest = redE[bg * 64 + lb]; kBest = redK[bg * 64 + lb];
#pragma unroll
        for (int g = 1; g < 4; ++g) {
            float oe = redE[bg * 64 + g * 16 + lb];
            int ok = redK[bg * 64 + g * 16 + lb];
            if (oe < eBest || (oe == eBest && ok < kBest)) { eBest = oe; kBest = ok; }
        }
    }
    if (kg == 0 && l < 16) {
        out[OUT_IDX + myb * H + h] = (float)kBest;
        ((int*)ws)[WS_IDX + myb * H + h] = kBest;
        atomicAdd(((unsigned*)ws) + WS_HIST + h * KK + kBest, 1u);
    }

    // pass C: probs -> block-partial avg_probs
    float invS = 1.0f / Sb;
#pragma unroll
    for (int tt = 0; tt < 32; ++tt) {
        f32x4 d = acc[tt];
        float p0 = __expf(Mb - d[0]) * invS;
        float p1 = __expf(Mb - d[1]) * invS;
        float p2 = __expf(Mb - d[2]) * invS;
        float p3 = __expf(Mb - d[3]) * invS;
#pragma unroll
        for (int off = 1; off < 16; off <<= 1) {
            p0 += __shfl_xor(p0, off);
            p1 += __shfl_xor(p1, off);
            p2 += __shfl_xor(p2, off);
            p3 += __shfl_xor(p3, off);
        }
        if (lb == 0) {
            int k0 = kbase + tt * 16 + lg * 4;
            atomicAdd(&paccL[k0 + 0], p0);
            atomicAdd(&paccL[k0 + 1], p1);
            atomicAdd(&paccL[k0 + 2], p2);
            atomicAdd(&paccL[k0 + 3], p3);
        }
    }
    __syncthreads();
    for (int i = t; i < 2048; i += 512)
        atomicAdd(ws + WS_AVGP + h * KK + i, paccL[i]);
}

// ---------------- k3: decode z_q and z_heads, z_q_st output, commit accum ----------------
__global__ __launch_bounds__(256, 2) void k3(const float* __restrict__ cb, const float* __restrict__ dw,
                                             const float* __restrict__ db, float* __restrict__ out,
                                             float* __restrict__ ws) {
    __shared__ float zqt[32][65];
    __shared__ float zht[32][65];
    __shared__ float dwt[64][128];
    __shared__ int idxs[32];
    __shared__ double redc[4];
    int t = threadIdx.x;
    int h = blockIdx.y;
    int b0 = blockIdx.x * 32;
    if (t < 32) idxs[t] = ((const int*)ws)[WS_IDX + (b0 + t) * H + h];
    __syncthreads();
#pragma unroll
    for (int p = 0; p < 8; ++p) {
        int q = t + 256 * p;
        int r = q >> 6, d = q & 63;
        zqt[r][d] = cb[(size_t)(h * KK + idxs[r]) * DD + d];
        zht[r][d] = out[OUT_ZH + (size_t)((b0 + r) * H + h) * DD + d];
    }
#pragma unroll
    for (int p = 0; p < 8; ++p) {
        int q = t + 256 * p;
        int r = q >> 5, c4 = q & 31;
        *(float4*)(&dwt[r][c4 * 4]) = *(const float4*)(dw + (size_t)(h * DD + r) * OO + c4 * 4);
    }
    __syncthreads();
    int rg = t >> 4, cg = t & 15;
    float aq[2][8], ap[2][8];
#pragma unroll
    for (int i = 0; i < 2; ++i)
#pragma unroll
        for (int j = 0; j < 8; ++j) { aq[i][j] = 0.f; ap[i][j] = 0.f; }
#pragma unroll 4
    for (int d = 0; d < 64; ++d) {
        float q0 = zqt[rg * 2][d], q1 = zqt[rg * 2 + 1][d];
        float p0 = zht[rg * 2][d], p1 = zht[rg * 2 + 1][d];
        float4 wa = *(const float4*)(&dwt[d][cg * 8]);
        float4 wb = *(const float4*)(&dwt[d][cg * 8 + 4]);
        float ww[8] = {wa.x, wa.y, wa.z, wa.w, wb.x, wb.y, wb.z, wb.w};
#pragma unroll
        for (int j = 0; j < 8; ++j) {
            aq[0][j] = fmaf(q0, ww[j], aq[0][j]);
            aq[1][j] = fmaf(q1, ww[j], aq[1][j]);
            ap[0][j] = fmaf(p0, ww[j], ap[0][j]);
            ap[1][j] = fmaf(p1, ww[j], ap[1][j]);
        }
    }
    float lsum = 0.f;
#pragma unroll
    for (int i = 0; i < 2; ++i) {
        float vq4[8];
#pragma unroll
        for (int j = 0; j < 8; ++j) {
            float bb = db[h * OO + cg * 8 + j];
            float vq = aq[i][j] + bb;
            float vp = ap[i][j] + bb;
            vq4[j] = vp + (vq - vp);
            float e = vp - vq;
            lsum = fmaf(e, e, lsum);
        }
        float4 s0 = {vq4[0], vq4[1], vq4[2], vq4[3]};
        float4 s1 = {vq4[4], vq4[5], vq4[6], vq4[7]};
        size_t o = (size_t)(b0 + rg * 2 + i) * HIDN + h * OO + cg * 8;
        *(float4*)(out + OUT_ZQ + o) = s0;
        *(float4*)(out + OUT_ZQ + o + 4) = s1;
    }
#pragma unroll
    for (int off = 1; off < 64; off <<= 1) lsum += __shfl_xor(lsum, off);
    if ((t & 63) == 0) redc[t >> 6] = (double)lsum;
    __syncthreads();
    if (t == 0) atomicAdd((double*)(ws + WS_ACC), redc[0] + redc[1] + redc[2] + redc[3]);
}

// ---------------- k6: ortho via LDS hash of co-occurrence pairs ----------------
__global__ __launch_bounds__(256) void k6(float* __restrict__ ws) {
    __shared__ unsigned slots[16384];
    __shared__ unsigned cnts[16384];
    int t = threadIdx.x;
    int bid = blockIdx.x;
    int pi = 0, pj = 1;
    {
        int c = 0;
        for (int a = 0; a < H; ++a)
            for (int b = a + 1; b < H; ++b) { if (c == bid) { pi = a; pj = b; } ++c; }
    }
    for (int s = t; s < 16384; s += 256) { slots[s] = 0xFFFFFFFFu; cnts[s] = 0u; }
    __syncthreads();
    const int* idxi = ((const int*)ws) + WS_IDX;
    for (int b = t; b < BB; b += 256) {
        unsigned key = ((unsigned)idxi[b * H + pi] << 11) | (unsigned)idxi[b * H + pj];
        unsigned p = (key * 2654435761u) >> 18;
        while (true) {
            unsigned old = atomicCAS(&slots[p], 0xFFFFFFFFu, key);
            if (old == 0xFFFFFFFFu || old == key) { atomicAdd(&cnts[p], 1u); break; }
            p = (p + 1) & 16383u;
        }
    }
    __syncthreads();
    const unsigned* hist = ((const unsigned*)ws) + WS_HIST;
    double loc = 0.0;
    for (int s = t; s < 16384; s += 256) {
        unsigned key = slots[s];
        if (key != 0xFFFFFFFFu) {
            int ki = (int)(key >> 11), kj = (int)(key & 2047u);
            float c = (float)cnts[s] * (1.0f / 8192.0f);
            float piv = (float)hist[pi * KK + ki] * (1.0f / 8192.0f);
            float pjv = (float)hist[pj * KK + kj] * (1.0f / 8192.0f);
            float e = piv * pjv;
            loc += (double)fabsf(c - e) - (double)e;
        }
    }
    double spi = 0.0, spj = 0.0;
    for (int k = t; k < KK; k += 256) {
        spi += (double)hist[pi * KK + k];
        spj += (double)hist[pj * KK + k];
    }
#pragma unroll
    for (int off = 1; off < 64; off <<= 1) {
        loc += __shfl_xor(loc, off);
        spi += __shfl_xor(spi, off);
        spj += __shfl_xor(spj, off);
    }
    __syncthreads();
    double* sc = (double*)cnts;
    if ((t & 63) == 0) { int w = t >> 6; sc[w] = loc; sc[4 + w] = spi; sc[8 + w] = spj; }
    __syncthreads();
    if (t == 0) {
        double L = sc[0] + sc[1] + sc[2] + sc[3];
        double SPI = (sc[4] + sc[5] + sc[6] + sc[7]) / 8192.0;
        double SPJ = (sc[8] + sc[9] + sc[10] + sc[11]) / 8192.0;
        atomicAdd(((double*)(ws + WS_ACC)) + 1, L + SPI * SPJ);
    }
}

// ---------------- k4: entropy_loss + scalar finalize ----------------
__global__ __launch_bounds__(256) void k4(float* __restrict__ out, float* __restrict__ ws) {
    __shared__ double red[256];
    int t = threadIdx.x;
    double tot = 0.0;
    for (int h = 0; h < H; ++h) {
        double s = 0.0;
        for (int k = t; k < KK; k += 256) {
            double a = (double)ws[WS_AVGP + h * KK + k] / 8192.0;
            s += a * log(a + 1e-8);
        }
        tot += s;
    }
    red[t] = tot;
    __syncthreads();
    for (int off = 128; off; off >>= 1) {
        if (t < off) red[t] += red[t + off];
        __syncthreads();
    }
    if (t == 0) {
        double entropy = -red[0] / 8.0;
        out[OUT_ENT] = (float)(1.0 - entropy / log(2048.0));
        double ca = *(const double*)(ws + WS_ACC);
        float cm = (float)(ca / (8192.0 * 1024.0));
        out[OUT_COMMIT] = cm;
        out[OUT_CBL] = cm;
        double oa = *(((const double*)(ws + WS_ACC)) + 1);
        out[OUT_ORTHO] = (float)(oa / (28.0 * 4194304.0));
    }
}

extern "C" void kernel_launch(void* const* d_in, const int* in_sizes, int n_in,
                              void* d_out, int out_size, void* d_ws, size_t ws_size,
                              hipStream_t stream) {
    (void)in_sizes; (void)n_in; (void)out_size; (void)ws_size;
    const float* z   = (const float*)d_in[0];
    const float* w1  = (const float*)d_in[1];
    const float* b1  = (const float*)d_in[2];
    const float* w2  = (const float*)d_in[3];
    const float* b2  = (const float*)d_in[4];
    const float* lng = (const float*)d_in[5];
    const float* lnb = (const float*)d_in[6];
    const float* cb  = (const float*)d_in[7];
    const float* dw  = (const float*)d_in[8];
    const float* db  = (const float*)d_in[9];
    float* out = (float*)d_out;
    float* ws = (float*)d_ws;

    hipMemsetAsync(ws + WS_AVGP, 0, WS_ZERO_BYTES, stream);
    k_pre<<<64, 256, 0, stream>>>(cb, ws);
    k1<<<dim3(128, 8), 256, 0, stream>>>(z, w1, b1, w2, b2, lng, lnb, out, ws);
    k2<<<dim3(256, 8), 512, 0, stream>>>(cb, out, ws);
    k3<<<dim3(256, 8), 256, 0, stream>>>(cb, dw, db, out, ws);
    k6<<<28, 256, 0, stream>>>(ws);
    k4<<<1, 256, 0, stream>>>(out, ws);
}